// Round 6
// baseline (392.456 us; speedup 1.0000x reference)
//
#include <hip/hip_runtime.h>
#include <hip/hip_bf16.h>
#include <cstdint>

typedef short v8s __attribute__((ext_vector_type(8)));
typedef float v4f __attribute__((ext_vector_type(4)));

#define DEV __device__ __forceinline__

DEV unsigned short f2bu(float f) {
  unsigned u = __builtin_bit_cast(unsigned, f);
  u += 0x7fffu + ((u >> 16) & 1u);   // RNE to bf16
  return (unsigned short)(u >> 16);
}

DEV v8s pack8(const float4& a, const float4& b) {
  v8s r;
  r[0] = (short)f2bu(a.x); r[1] = (short)f2bu(a.y);
  r[2] = (short)f2bu(a.z); r[3] = (short)f2bu(a.w);
  r[4] = (short)f2bu(b.x); r[5] = (short)f2bu(b.y);
  r[6] = (short)f2bu(b.z); r[7] = (short)f2bu(b.w);
  return r;
}

// ---------------- K1: deg -> dinv = rsqrt(1 + rowsum(A)); optional A->bf16 ----------------
template<bool CVT>
__global__ __launch_bounds__(256)
void k_degcvt(const float* __restrict__ A, float* __restrict__ dinv,
              unsigned short* __restrict__ Abf) {
  const int row = blockIdx.x;
  const float* ar = A + (size_t)row * 8192;
  unsigned short* aw = Abf + (size_t)row * 8192;
  float s = 0.f;
  #pragma unroll
  for (int i = 0; i < 8; ++i) {
    const int c = i * 1024 + threadIdx.x * 4;
    float4 v = *(const float4*)(ar + c);
    s += (v.x + v.y) + (v.z + v.w);
    if constexpr (CVT) {
      uint2 w;
      w.x = (unsigned)f2bu(v.x) | ((unsigned)f2bu(v.y) << 16);
      w.y = (unsigned)f2bu(v.z) | ((unsigned)f2bu(v.w) << 16);
      *(uint2*)(aw + c) = w;
    }
  }
  #pragma unroll
  for (int d = 1; d < 64; d <<= 1) s += __shfl_xor(s, d);
  __shared__ float wsum[4];
  if ((threadIdx.x & 63) == 0) wsum[threadIdx.x >> 6] = s;
  __syncthreads();
  if (threadIdx.x == 0) {
    dinv[row] = rsqrtf(1.0f + ((wsum[0] + wsum[1]) + (wsum[2] + wsum[3])));
  }
}

// -------- K2: X [8192][128] f32 -> xpt [128][8192] bf16, row-scaled by dinv --------
template<bool SCALE>
__global__ __launch_bounds__(256)
void k_transpose(const float* __restrict__ in, unsigned short* __restrict__ out,
                 const float* __restrict__ dinv) {
  __shared__ float tile[32][129];
  const int j0 = blockIdx.x * 32;
  const int t = threadIdx.x;
  const int r0 = t >> 5, sl = t & 31;
  #pragma unroll
  for (int i = 0; i < 4; ++i) {
    int r = r0 + i * 8;
    float4 v = *(const float4*)(in + (size_t)(j0 + r) * 128 + sl * 4);
    float sc = 1.0f;
    if constexpr (SCALE) sc = dinv[j0 + r];
    tile[r][sl * 4 + 0] = v.x * sc;
    tile[r][sl * 4 + 1] = v.y * sc;
    tile[r][sl * 4 + 2] = v.z * sc;
    tile[r][sl * 4 + 3] = v.w * sc;
  }
  __syncthreads();
  const int c = t >> 1, h = t & 1;
  unsigned short* op = out + (size_t)c * 8192 + j0 + h * 16;
  #pragma unroll
  for (int q = 0; q < 2; ++q) {
    int rb = h * 16 + q * 8;
    uint4 w;
    w.x = (unsigned)f2bu(tile[rb + 0][c]) | ((unsigned)f2bu(tile[rb + 1][c]) << 16);
    w.y = (unsigned)f2bu(tile[rb + 2][c]) | ((unsigned)f2bu(tile[rb + 3][c]) << 16);
    w.z = (unsigned)f2bu(tile[rb + 4][c]) | ((unsigned)f2bu(tile[rb + 5][c]) << 16);
    w.w = (unsigned)f2bu(tile[rb + 6][c]) | ((unsigned)f2bu(tile[rb + 7][c]) << 16);
    *(uint4*)(op + q * 8) = w;
  }
}

// -------- K3/K4: fused full-K GEMM (no split-K partials) + fused epilogue --------
// Grid 256 x 512thr (8 waves). Block = 32 rows x 128 cols, full K=8192.
// Wave wv: rows 0..31 (acc[2]), cols wv*16..+15. B chunk [128c][128k] dbuf LDS
// swizzled; A whole-chunk (128k) reg prefetch dbuf. EPI1: AX epi + z/logit MFMA
// + softmax -> sl, slt, zlt.  EPI2: As -> ast (bf16 transposed).
#define LOADA(AR, C) do {                                                       \
    _Pragma("unroll")                                                           \
    for (int kf = 0; kf < 4; ++kf) {                                            \
      AR[kf][0] = *(const v8s*)(pA0 + (C) * 128 + kf * 32);                     \
      AR[kf][1] = *(const v8s*)(pA1 + (C) * 128 + kf * 32);                     \
    }                                                                           \
  } while (0)

#define MFMA_CHUNK(BUF, AR, C) do {                                             \
    _Pragma("unroll")                                                           \
    for (int ks = 0; ks < 4; ++ks) {                                            \
      const int boff = ((col << 8) + ks * 64 + lq * 16) ^ ((col & 7) << 4);     \
      v8s bf = *(const v8s*)((BUF) + boff);                                     \
      v8s a0_, a1_;                                                             \
      if constexpr (ABF) { a0_ = AR[ks][0]; a1_ = AR[ks][1]; }                  \
      else {                                                                    \
        a0_ = pack8(*(const float4*)(pAf0 + (size_t)(C) * 128 + ks * 32),       \
                    *(const float4*)(pAf0 + (size_t)(C) * 128 + ks * 32 + 4));  \
        a1_ = pack8(*(const float4*)(pAf1 + (size_t)(C) * 128 + ks * 32),       \
                    *(const float4*)(pAf1 + (size_t)(C) * 128 + ks * 32 + 4));  \
      }                                                                         \
      acc[0] = __builtin_amdgcn_mfma_f32_16x16x32_bf16(a0_, bf, acc[0], 0, 0, 0); \
      acc[1] = __builtin_amdgcn_mfma_f32_16x16x32_bf16(a1_, bf, acc[1], 0, 0, 0); \
    }                                                                           \
  } while (0)

template<int EPI, bool ABF>
__global__ __launch_bounds__(512, 2)
void k_gemm_fused(const float* __restrict__ Af, const unsigned short* __restrict__ Ab16,
                  const unsigned short* __restrict__ Bt,
                  const float* __restrict__ dinv, const float* __restrict__ Xg,
                  const float* __restrict__ We, const float* __restrict__ be,
                  const float* __restrict__ Wa, const float* __restrict__ ba,
                  float* __restrict__ sl_out, unsigned short* __restrict__ slt,
                  unsigned short* __restrict__ zlt, unsigned short* __restrict__ ast) {
  __shared__ alignas(16) char smem[65536];
  char* bsm0 = smem;
  char* bsm1 = smem + 32768;
  const int t = threadIdx.x;
  const int wv = t >> 6, l = t & 63;
  const int lr = l & 15, lq = l >> 4;
  const int i0 = blockIdx.x * 32;
  const int col = wv * 16 + lr;

  const unsigned short* pA0 = Ab16 + (size_t)(i0 + lr) * 8192 + lq * 8;
  const unsigned short* pA1 = pA0 + (size_t)16 * 8192;
  const float* pAf0 = Af + (size_t)(i0 + lr) * 8192 + lq * 8;
  const float* pAf1 = pAf0 + (size_t)16 * 8192;

  // B staging coords: thread t -> cols sc+32i, 16B at k-slot (t&15)*8
  const int sc = t >> 4, sk16 = t & 15;
  const unsigned short* pS = Bt + (size_t)sc * 8192 + sk16 * 8;
  int woff[4];
  #pragma unroll
  for (int i = 0; i < 4; ++i) {
    const int c = sc + i * 32;
    woff[i] = ((c << 8) + sk16 * 16) ^ ((c & 7) << 4);
  }

  v4f acc[2] = {{0.f,0.f,0.f,0.f},{0.f,0.f,0.f,0.f}};
  v8s breg[4];
  v8s aA[4][2], aB[4][2];

  auto stage_load = [&](int c) {
    #pragma unroll
    for (int i = 0; i < 4; ++i)
      breg[i] = *(const v8s*)(pS + (size_t)i * 32 * 8192 + c * 128);
  };
  auto stage_write = [&](char* buf) {
    #pragma unroll
    for (int i = 0; i < 4; ++i)
      *(v8s*)(buf + woff[i]) = breg[i];
  };

  stage_load(0);
  stage_write(bsm0);
  if constexpr (ABF) LOADA(aA, 0);
  __syncthreads();

  for (int c = 0; c < 64; c += 2) {
    // even chunk: bsm0 / aA
    stage_load(c + 1);
    if constexpr (ABF) LOADA(aB, c + 1);
    MFMA_CHUNK(bsm0, aA, c);
    __syncthreads();
    stage_write(bsm1);
    __syncthreads();
    // odd chunk: bsm1 / aB
    if (c + 2 < 64) {
      stage_load(c + 2);
      if constexpr (ABF) LOADA(aA, c + 2);
    }
    MFMA_CHUNK(bsm1, aB, c + 1);
    __syncthreads();
    if (c + 2 < 64) {
      stage_write(bsm0);
      __syncthreads();
    }
  }
  __syncthreads();   // K-loop reads done; smem reusable

  if constexpr (EPI == 1) {
    unsigned short* axs = (unsigned short*)smem;            // 8192 B swizzled AX
    float* lg           = (float*)(smem + 8192);            // 16384 B logits
    unsigned short* zbf = (unsigned short*)(smem + 24576);  // 32*130*2
    unsigned short* sbf = (unsigned short*)(smem + 32896);  // 32*130*2

    { // Phase A: AX = di*(acc + di*X) -> swizzled bf16 LDS
      #pragma unroll
      for (int mt = 0; mt < 2; ++mt)
        #pragma unroll
        for (int r = 0; r < 4; ++r) {
          const int row = mt * 16 + lq * 4 + r;
          const int gi = i0 + row;
          const float di = dinv[gi];
          const float ax = di * (acc[mt][r] + di * Xg[(size_t)gi * 128 + col]);
          const int off = ((row << 8) + col * 2) ^ ((row & 7) << 4);
          *(unsigned short*)((char*)axs + off) = f2bu(ax);
        }
    }
    __syncthreads();

    { // Phase B: z = AX@We^T + be, logits = AX@Wa^T + ba
      v4f zac[2] = {{0.f,0.f,0.f,0.f},{0.f,0.f,0.f,0.f}};
      v4f lac[2] = {{0.f,0.f,0.f,0.f},{0.f,0.f,0.f,0.f}};
      const int kk = lq * 8;
      #pragma unroll
      for (int ks = 0; ks < 4; ++ks) {
        const int k = ks * 32 + kk;
        v8s bfe = pack8(*(const float4*)(We + col * 128 + k),
                        *(const float4*)(We + col * 128 + k + 4));
        v8s bfa = pack8(*(const float4*)(Wa + col * 128 + k),
                        *(const float4*)(Wa + col * 128 + k + 4));
        #pragma unroll
        for (int mt = 0; mt < 2; ++mt) {
          const int arow = mt * 16 + lr;
          v8s af = *(const v8s*)((char*)axs + (((arow << 8) + k * 2) ^ ((lr & 7) << 4)));
          zac[mt] = __builtin_amdgcn_mfma_f32_16x16x32_bf16(af, bfe, zac[mt], 0, 0, 0);
          lac[mt] = __builtin_amdgcn_mfma_f32_16x16x32_bf16(af, bfa, lac[mt], 0, 0, 0);
        }
      }
      const float bev = be[col], bav = ba[col];
      #pragma unroll
      for (int mt = 0; mt < 2; ++mt)
        #pragma unroll
        for (int r4 = 0; r4 < 4; ++r4) {
          const int row = mt * 16 + lq * 4 + r4;
          lg[row * 128 + col] = lac[mt][r4] + bav;
          zbf[row * 130 + col] = f2bu(zac[mt][r4] + bev);
        }
    }
    __syncthreads();

    { // Phase D: softmax, 16 threads/row, 8 cols each
      const int r = t >> 4, g = t & 15;
      const float* lp = lg + r * 128 + g * 8;
      float4 v0 = *(const float4*)(lp);
      float4 v1 = *(const float4*)(lp + 4);
      float x[8] = {v0.x, v0.y, v0.z, v0.w, v1.x, v1.y, v1.z, v1.w};
      float mx = x[0];
      #pragma unroll
      for (int j = 1; j < 8; ++j) mx = fmaxf(mx, x[j]);
      #pragma unroll
      for (int d = 1; d < 16; d <<= 1) mx = fmaxf(mx, __shfl_xor(mx, d));
      float sum = 0.f;
      #pragma unroll
      for (int j = 0; j < 8; ++j) { x[j] = __expf(x[j] - mx); sum += x[j]; }
      #pragma unroll
      for (int d = 1; d < 16; d <<= 1) sum += __shfl_xor(sum, d);
      const float inv = 1.0f / sum;
      float* op = sl_out + (size_t)(i0 + r) * 128 + g * 8;
      *(float4*)(op)     = make_float4(x[0]*inv, x[1]*inv, x[2]*inv, x[3]*inv);
      *(float4*)(op + 4) = make_float4(x[4]*inv, x[5]*inv, x[6]*inv, x[7]*inv);
      #pragma unroll
      for (int j = 0; j < 8; ++j) sbf[r * 130 + g * 8 + j] = f2bu(x[j] * inv);
    }
    __syncthreads();

    if (t < 256) { // Phase E: transposed bf16 writes
      const int c = t & 127;
      const unsigned short* src = (t < 128) ? sbf : zbf;
      unsigned short* dst = (t < 128) ? slt : zlt;
      unsigned short* o = dst + (size_t)c * 8192 + i0;
      #pragma unroll
      for (int q = 0; q < 4; ++q) {
        uint4 w;
        w.x = (unsigned)src[(q * 8 + 0) * 130 + c] | ((unsigned)src[(q * 8 + 1) * 130 + c] << 16);
        w.y = (unsigned)src[(q * 8 + 2) * 130 + c] | ((unsigned)src[(q * 8 + 3) * 130 + c] << 16);
        w.z = (unsigned)src[(q * 8 + 4) * 130 + c] | ((unsigned)src[(q * 8 + 5) * 130 + c] << 16);
        w.w = (unsigned)src[(q * 8 + 6) * 130 + c] | ((unsigned)src[(q * 8 + 7) * 130 + c] << 16);
        *(uint4*)(o + q * 8) = w;
      }
    }
  } else {
    unsigned short* sb = (unsigned short*)smem;   // [32][130] bf16 As
    #pragma unroll
    for (int mt = 0; mt < 2; ++mt)
      #pragma unroll
      for (int r = 0; r < 4; ++r) {
        const int row = mt * 16 + lq * 4 + r;
        sb[row * 130 + col] = f2bu(acc[mt][r]);
      }
    __syncthreads();
    if (t < 128) {
      unsigned short* o = ast + (size_t)t * 8192 + i0;
      #pragma unroll
      for (int q = 0; q < 4; ++q) {
        uint4 w;
        w.x = (unsigned)sb[(q * 8 + 0) * 130 + t] | ((unsigned)sb[(q * 8 + 1) * 130 + t] << 16);
        w.y = (unsigned)sb[(q * 8 + 2) * 130 + t] | ((unsigned)sb[(q * 8 + 3) * 130 + t] << 16);
        w.z = (unsigned)sb[(q * 8 + 4) * 130 + t] | ((unsigned)sb[(q * 8 + 5) * 130 + t] << 16);
        w.w = (unsigned)sb[(q * 8 + 6) * 130 + t] | ((unsigned)sb[(q * 8 + 7) * 130 + t] << 16);
        *(uint4*)(o + q * 8) = w;
      }
    }
  }
}

// -------- K5: split-K outer products: X_next = s^T z, A_next = s^T (A s) --------
__global__ __launch_bounds__(256)
void k_outer(const unsigned short* __restrict__ slt, const unsigned short* __restrict__ zlt,
             const unsigned short* __restrict__ ast, float* __restrict__ parts) {
  const int t = threadIdx.x, wv = t >> 6, ln = t & 63;
  const int k0 = blockIdx.x * 128;
  const int lm = ln & 15, lk = (ln >> 4) << 3;
  v4f c1[2][8];
  v4f c2[2][8];
  #pragma unroll
  for (int mt = 0; mt < 2; ++mt)
    #pragma unroll
    for (int nt = 0; nt < 8; ++nt) { c1[mt][nt] = (v4f){0.f,0.f,0.f,0.f}; c2[mt][nt] = (v4f){0.f,0.f,0.f,0.f}; }
  #pragma unroll
  for (int ks = 0; ks < 4; ++ks) {
    int k = k0 + ks * 32 + lk;
    v8s a0 = *(const v8s*)(slt + (size_t)(wv * 32 + lm) * 8192 + k);
    v8s a1 = *(const v8s*)(slt + (size_t)(wv * 32 + 16 + lm) * 8192 + k);
    #pragma unroll
    for (int nt = 0; nt < 8; ++nt) {
      v8s bz = *(const v8s*)(zlt + (size_t)(nt * 16 + lm) * 8192 + k);
      v8s bs = *(const v8s*)(ast + (size_t)(nt * 16 + lm) * 8192 + k);
      c1[0][nt] = __builtin_amdgcn_mfma_f32_16x16x32_bf16(a0, bz, c1[0][nt], 0, 0, 0);
      c1[1][nt] = __builtin_amdgcn_mfma_f32_16x16x32_bf16(a1, bz, c1[1][nt], 0, 0, 0);
      c2[0][nt] = __builtin_amdgcn_mfma_f32_16x16x32_bf16(a0, bs, c2[0][nt], 0, 0, 0);
      c2[1][nt] = __builtin_amdgcn_mfma_f32_16x16x32_bf16(a1, bs, c2[1][nt], 0, 0, 0);
    }
  }
  float* p = parts + (size_t)blockIdx.x * 32768;
  #pragma unroll
  for (int mt = 0; mt < 2; ++mt)
    #pragma unroll
    for (int nt = 0; nt < 8; ++nt)
      #pragma unroll
      for (int r = 0; r < 4; ++r) {
        int m = wv * 32 + mt * 16 + ((ln >> 4) << 2) + r;
        int n = nt * 16 + lm;
        p[m * 128 + n] = c1[mt][nt][r];
        p[16384 + m * 128 + n] = c2[mt][nt][r];
      }
}

// -------- K6: reduce outer partials -> X_next, A_next --------
__global__ __launch_bounds__(256)
void k_reduce(const float* __restrict__ parts, float* __restrict__ out) {
  const int o = blockIdx.x * 256 + threadIdx.x;   // < 32768
  float s = 0.f;
  for (int b = 0; b < 64; ++b) s += parts[(size_t)b * 32768 + o];
  out[o] = s;
}

extern "C" void kernel_launch(void* const* d_in, const int* in_sizes, int n_in,
                              void* d_out, int out_size, void* d_ws, size_t ws_size,
                              hipStream_t stream) {
  (void)in_sizes; (void)n_in; (void)out_size;
  const float* X  = (const float*)d_in[0];
  const float* A  = (const float*)d_in[1];
  const float* We = (const float*)d_in[2];
  const float* be = (const float*)d_in[3];
  const float* Wa = (const float*)d_in[4];
  const float* ba = (const float*)d_in[5];
  float* out = (float*)d_out;
  float* sl = out + 32768;            // s_l region of d_out

  char* ws = (char*)d_ws;
  constexpr size_t OFF_XPT  = 32768;
  constexpr size_t OFF_SLT  = OFF_XPT + 2097152;
  constexpr size_t OFF_ZLT  = OFF_SLT + 2097152;
  constexpr size_t OFF_AST  = OFF_ZLT + 2097152;
  constexpr size_t OFF_PART = OFF_AST + 2097152;     // outer partials (8.4 MB used)
  constexpr size_t OFF_ABF  = OFF_PART + 67108864;
  constexpr size_t NEED_ABF = OFF_ABF + 134217728ull;

  float*          dinv = (float*)(ws + 0);
  unsigned short* xpt  = (unsigned short*)(ws + OFF_XPT);
  unsigned short* slt  = (unsigned short*)(ws + OFF_SLT);
  unsigned short* zlt  = (unsigned short*)(ws + OFF_ZLT);
  unsigned short* ast  = (unsigned short*)(ws + OFF_AST);
  float*          part = (float*)(ws + OFF_PART);
  unsigned short* abfp = (unsigned short*)(ws + OFF_ABF);

  const bool abf = ws_size >= NEED_ABF;

  if (abf) k_degcvt<true><<<8192, 256, 0, stream>>>(A, dinv, abfp);
  else     k_degcvt<false><<<8192, 256, 0, stream>>>(A, dinv, abfp);

  k_transpose<true><<<256, 256, 0, stream>>>(X, xpt, dinv);

  if (abf)
    k_gemm_fused<1, true><<<256, 512, 0, stream>>>(A, abfp, xpt, dinv, X, We, be, Wa, ba,
                                                   sl, slt, zlt, nullptr);
  else
    k_gemm_fused<1, false><<<256, 512, 0, stream>>>(A, abfp, xpt, dinv, X, We, be, Wa, ba,
                                                    sl, slt, zlt, nullptr);

  if (abf)
    k_gemm_fused<2, true><<<256, 512, 0, stream>>>(A, abfp, slt, nullptr, nullptr,
                                                   nullptr, nullptr, nullptr, nullptr,
                                                   nullptr, nullptr, nullptr, ast);
  else
    k_gemm_fused<2, false><<<256, 512, 0, stream>>>(A, abfp, slt, nullptr, nullptr,
                                                    nullptr, nullptr, nullptr, nullptr,
                                                    nullptr, nullptr, nullptr, ast);

  k_outer<<<64, 256, 0, stream>>>(slt, zlt, ast, part);
  k_reduce<<<128, 256, 0, stream>>>(part, out);
}

// Round 7
// 203.839 us; speedup vs baseline: 1.9253x; 1.9253x over previous
//
#include <hip/hip_runtime.h>
#include <hip/hip_bf16.h>
#include <cstdint>

typedef short v8s __attribute__((ext_vector_type(8)));
typedef float v4f __attribute__((ext_vector_type(4)));

#define DEV __device__ __forceinline__

DEV unsigned short f2bu(float f) {
  unsigned u = __builtin_bit_cast(unsigned, f);
  u += 0x7fffu + ((u >> 16) & 1u);   // RNE to bf16
  return (unsigned short)(u >> 16);
}

DEV v8s pack8(const float4& a, const float4& b) {
  v8s r;
  r[0] = (short)f2bu(a.x); r[1] = (short)f2bu(a.y);
  r[2] = (short)f2bu(a.z); r[3] = (short)f2bu(a.w);
  r[4] = (short)f2bu(b.x); r[5] = (short)f2bu(b.y);
  r[6] = (short)f2bu(b.z); r[7] = (short)f2bu(b.w);
  return r;
}

// ---------------- K1: deg -> dinv = rsqrt(1 + rowsum(A)); optional A->bf16 ----------------
template<bool CVT>
__global__ __launch_bounds__(256)
void k_degcvt(const float* __restrict__ A, float* __restrict__ dinv,
              unsigned short* __restrict__ Abf) {
  const int row = blockIdx.x;
  const float* ar = A + (size_t)row * 8192;
  unsigned short* aw = Abf + (size_t)row * 8192;
  float s = 0.f;
  #pragma unroll
  for (int i = 0; i < 8; ++i) {
    const int c = i * 1024 + threadIdx.x * 4;
    float4 v = *(const float4*)(ar + c);
    s += (v.x + v.y) + (v.z + v.w);
    if constexpr (CVT) {
      uint2 w;
      w.x = (unsigned)f2bu(v.x) | ((unsigned)f2bu(v.y) << 16);
      w.y = (unsigned)f2bu(v.z) | ((unsigned)f2bu(v.w) << 16);
      *(uint2*)(aw + c) = w;
    }
  }
  #pragma unroll
  for (int d = 1; d < 64; d <<= 1) s += __shfl_xor(s, d);
  __shared__ float wsum[4];
  if ((threadIdx.x & 63) == 0) wsum[threadIdx.x >> 6] = s;
  __syncthreads();
  if (threadIdx.x == 0) {
    dinv[row] = rsqrtf(1.0f + ((wsum[0] + wsum[1]) + (wsum[2] + wsum[3])));
  }
}

// -------- K2: X [8192][128] f32 -> xpt [128][8192] bf16, row-scaled by dinv --------
template<bool SCALE>
__global__ __launch_bounds__(256)
void k_transpose(const float* __restrict__ in, unsigned short* __restrict__ out,
                 const float* __restrict__ dinv) {
  __shared__ float tile[32][129];
  const int j0 = blockIdx.x * 32;
  const int t = threadIdx.x;
  const int r0 = t >> 5, sl = t & 31;
  #pragma unroll
  for (int i = 0; i < 4; ++i) {
    int r = r0 + i * 8;
    float4 v = *(const float4*)(in + (size_t)(j0 + r) * 128 + sl * 4);
    float sc = 1.0f;
    if constexpr (SCALE) sc = dinv[j0 + r];
    tile[r][sl * 4 + 0] = v.x * sc;
    tile[r][sl * 4 + 1] = v.y * sc;
    tile[r][sl * 4 + 2] = v.z * sc;
    tile[r][sl * 4 + 3] = v.w * sc;
  }
  __syncthreads();
  const int c = t >> 1, h = t & 1;
  unsigned short* op = out + (size_t)c * 8192 + j0 + h * 16;
  #pragma unroll
  for (int q = 0; q < 2; ++q) {
    int rb = h * 16 + q * 8;
    uint4 w;
    w.x = (unsigned)f2bu(tile[rb + 0][c]) | ((unsigned)f2bu(tile[rb + 1][c]) << 16);
    w.y = (unsigned)f2bu(tile[rb + 2][c]) | ((unsigned)f2bu(tile[rb + 3][c]) << 16);
    w.z = (unsigned)f2bu(tile[rb + 4][c]) | ((unsigned)f2bu(tile[rb + 5][c]) << 16);
    w.w = (unsigned)f2bu(tile[rb + 6][c]) | ((unsigned)f2bu(tile[rb + 7][c]) << 16);
    *(uint4*)(op + q * 8) = w;
  }
}

// -------- K3/K5 (main): LDS-B split-K GEMM: part[ks] = Abf[rows, kslice] @ B^T --------
// Block: 512 thr = 8 waves, 128 rows x 128 cols; wave = 32r x 64c (acc 2x4).
// SPLITK=8 -> k-slice 1024 = 8 chunks of BK=128.
// B chunk [128c][128k] double-buffered LDS (2x32KB), XOR-swizzled, reg-staged.
// A: whole-chunk register prefetch, double-buffered.
// SINGLE barrier per chunk: stage_write targets the other buffer, so the only
// hazard (write c+2 vs reads of c) is already fenced by the one barrier.
// __launch_bounds__(512,4) pins VGPR<=128 -> 2 blocks/CU (R6 showed 1/CU is fatal).
__global__ __launch_bounds__(512, 4)
void k_gemm_lds(const unsigned short* __restrict__ Ab16,
                const unsigned short* __restrict__ Bt, float* __restrict__ parts) {
  __shared__ alignas(16) char bsm[2][32768];
  const int t = threadIdx.x;
  const int wv = t >> 6, l = t & 63;
  const int rg = wv >> 1, wc = wv & 1;
  const int i0 = blockIdx.x * 128 + rg * 32;
  const int k0 = blockIdx.y * 1024;
  const int lr = l & 15, lq = l >> 4;

  const unsigned short* pA0 = Ab16 + (size_t)(i0 + lr) * 8192 + k0 + lq * 8;
  const unsigned short* pA1 = pA0 + (size_t)16 * 8192;

  // staging: thread t loads cols sc+32i, 16B at k-slot (t&15)*8 within 128-k chunk
  const int sc = t >> 4, sk16 = t & 15;
  const unsigned short* pS = Bt + (size_t)sc * 8192 + k0 + sk16 * 8;
  int woff[4];
  #pragma unroll
  for (int i = 0; i < 4; ++i) {
    const int c = sc + i * 32;
    woff[i] = ((c << 8) + sk16 * 16) ^ ((c & 7) << 4);
  }

  v4f acc[2][4];
  #pragma unroll
  for (int mt = 0; mt < 2; ++mt)
    #pragma unroll
    for (int nt = 0; nt < 4; ++nt) acc[mt][nt] = (v4f){0.f, 0.f, 0.f, 0.f};

  v8s breg[4];
  v8s areg[2][4][2];   // [buf][kf][mt] -- all indices compile-time (full unroll)

  auto stage_load = [&](int c) {
    #pragma unroll
    for (int i = 0; i < 4; ++i)
      breg[i] = *(const v8s*)(pS + (size_t)i * 32 * 8192 + c * 128);
  };
  auto stage_write = [&](int buf) {
    #pragma unroll
    for (int i = 0; i < 4; ++i)
      *(v8s*)(bsm[buf] + woff[i]) = breg[i];
  };

  stage_load(0);
  stage_write(0);
  #pragma unroll
  for (int kf = 0; kf < 4; ++kf) {        // A chunk 0
    areg[0][kf][0] = *(const v8s*)(pA0 + kf * 32);
    areg[0][kf][1] = *(const v8s*)(pA1 + kf * 32);
  }
  __syncthreads();

  #pragma unroll
  for (int c = 0; c < 8; ++c) {
    if (c < 7) {
      stage_load(c + 1);
      #pragma unroll
      for (int kf = 0; kf < 4; ++kf) {    // A chunk c+1 into other buffer
        areg[(c + 1) & 1][kf][0] = *(const v8s*)(pA0 + (c + 1) * 128 + kf * 32);
        areg[(c + 1) & 1][kf][1] = *(const v8s*)(pA1 + (c + 1) * 128 + kf * 32);
      }
    }
    #pragma unroll
    for (int ks = 0; ks < 4; ++ks) {
      #pragma unroll
      for (int nt = 0; nt < 4; ++nt) {
        const int col = wc * 64 + nt * 16 + lr;
        const int off = (((col << 8) + ks * 64 + lq * 16) ^ ((col & 7) << 4));
        v8s bf = *(const v8s*)(bsm[c & 1] + off);
        acc[0][nt] = __builtin_amdgcn_mfma_f32_16x16x32_bf16(areg[c & 1][ks][0], bf, acc[0][nt], 0, 0, 0);
        acc[1][nt] = __builtin_amdgcn_mfma_f32_16x16x32_bf16(areg[c & 1][ks][1], bf, acc[1][nt], 0, 0, 0);
      }
    }
    if (c < 7) {
      stage_write((c + 1) & 1);   // other buffer: no conflict with chunk-c reads
      __syncthreads();            // fences both LDS visibility and buffer reuse
    }
  }

  float* p = parts + (size_t)blockIdx.y * (8192 * 128);
  const int colb = wc * 64;
  #pragma unroll
  for (int mt = 0; mt < 2; ++mt)
    #pragma unroll
    for (int nt = 0; nt < 4; ++nt)
      #pragma unroll
      for (int r = 0; r < 4; ++r)
        p[(size_t)(i0 + mt * 16 + lq * 4 + r) * 128 + colb + nt * 16 + lr] = acc[mt][nt][r];
}

// -------- fallback GEMM (small ws): reg-only f32 A, split-K=4 --------
__global__ __launch_bounds__(512)
void k_gemm_f32(const float* __restrict__ Af, const unsigned short* __restrict__ Bt,
                float* __restrict__ parts) {
  constexpr int KSTEPS = 2048 / 32;
  const int t = threadIdx.x;
  const int wv = t >> 6, l = t & 63;
  const int rg = wv >> 1, ch = wv & 1;
  const int i0 = blockIdx.x * 128 + rg * 32;
  const int k0 = blockIdx.y * 2048;
  const int lr = l & 15, lk = (l >> 4) * 8;

  const float* pAf0 = Af + (size_t)(i0 + lr) * 8192 + k0 + lk;
  const float* pAf1 = pAf0 + (size_t)16 * 8192;
  const unsigned short* pB[4];
  #pragma unroll
  for (int nt = 0; nt < 4; ++nt)
    pB[nt] = Bt + (size_t)(ch * 64 + nt * 16 + lr) * 8192 + k0 + lk;

  v4f acc[2][4];
  #pragma unroll
  for (int mt = 0; mt < 2; ++mt)
    #pragma unroll
    for (int nt = 0; nt < 4; ++nt) acc[mt][nt] = (v4f){0.f, 0.f, 0.f, 0.f};

  float4 af_[2][2][2];
  v8s bb[2][4];

  auto loadab = [&](int buf, int k) {
    af_[buf][0][0] = *(const float4*)(pAf0 + k);
    af_[buf][0][1] = *(const float4*)(pAf0 + k + 4);
    af_[buf][1][0] = *(const float4*)(pAf1 + k);
    af_[buf][1][1] = *(const float4*)(pAf1 + k + 4);
    #pragma unroll
    for (int nt = 0; nt < 4; ++nt) bb[buf][nt] = *(const v8s*)(pB[nt] + k);
  };
  auto mfmas = [&](int buf) {
    #pragma unroll
    for (int mt = 0; mt < 2; ++mt) {
      v8s a_ = pack8(af_[buf][mt][0], af_[buf][mt][1]);
      #pragma unroll
      for (int nt = 0; nt < 4; ++nt)
        acc[mt][nt] = __builtin_amdgcn_mfma_f32_16x16x32_bf16(a_, bb[buf][nt], acc[mt][nt], 0, 0, 0);
    }
  };

  loadab(0, 0);
  for (int kt = 0; kt < KSTEPS; kt += 2) {
    loadab(1, (kt + 1) * 32);
    mfmas(0);
    if (kt + 2 < KSTEPS) loadab(0, (kt + 2) * 32);
    mfmas(1);
  }

  float* p = parts + (size_t)blockIdx.y * (8192 * 128);
  const int colb = ch * 64;
  #pragma unroll
  for (int mt = 0; mt < 2; ++mt)
    #pragma unroll
    for (int nt = 0; nt < 4; ++nt)
      #pragma unroll
      for (int r = 0; r < 4; ++r)
        p[(size_t)(i0 + mt * 16 + (l >> 4) * 4 + r) * 128 + colb + nt * 16 + lr] = acc[mt][nt][r];
}

// -------- K4: reduce GEMM1 partials + epilogue + z/logit MFMA + softmax + T-writes --------
__global__ __launch_bounds__(256)
void k_post1(const float* __restrict__ parts, int nsplit,
             const float* __restrict__ dinv, const float* __restrict__ Xg,
             const float* __restrict__ We, const float* __restrict__ be,
             const float* __restrict__ Wa, const float* __restrict__ ba,
             float* __restrict__ sl_out, unsigned short* __restrict__ slt,
             unsigned short* __restrict__ zlt) {
  __shared__ alignas(16) unsigned short axs[32 * 128];   // swizzled bf16 AX
  __shared__ float lg[32 * 128];                          // logits f32
  __shared__ unsigned short sbf[32 * 130];
  __shared__ unsigned short zbf[32 * 130];
  const int t = threadIdx.x;
  const int i0 = blockIdx.x * 32;

  { // Phase A: sum partials, epilogue AX = di*(acc + di*X), bf16 -> swizzled LDS
    const int r = t >> 3, cg = t & 7;
    const size_t base = (size_t)(i0 + r) * 128 + cg * 16;
    float acc[16];
    #pragma unroll
    for (int q = 0; q < 4; ++q) {
      float4 v = *(const float4*)(parts + base + q * 4);
      acc[q * 4 + 0] = v.x; acc[q * 4 + 1] = v.y;
      acc[q * 4 + 2] = v.z; acc[q * 4 + 3] = v.w;
    }
    for (int s = 1; s < nsplit; ++s) {
      #pragma unroll
      for (int q = 0; q < 4; ++q) {
        float4 v = *(const float4*)(parts + (size_t)s * 1048576 + base + q * 4);
        acc[q * 4 + 0] += v.x; acc[q * 4 + 1] += v.y;
        acc[q * 4 + 2] += v.z; acc[q * 4 + 3] += v.w;
      }
    }
    const float di = dinv[i0 + r];
    unsigned short bx[16];
    #pragma unroll
    for (int q = 0; q < 4; ++q) {
      float4 xv = *(const float4*)(Xg + base + q * 4);
      bx[q * 4 + 0] = f2bu(di * (acc[q * 4 + 0] + di * xv.x));
      bx[q * 4 + 1] = f2bu(di * (acc[q * 4 + 1] + di * xv.y));
      bx[q * 4 + 2] = f2bu(di * (acc[q * 4 + 2] + di * xv.z));
      bx[q * 4 + 3] = f2bu(di * (acc[q * 4 + 3] + di * xv.w));
    }
    char* Ab = (char*)axs;
    const int b0 = (r << 8) + cg * 32, sw = (r & 7) << 4;
    uint4 w0, w1;
    w0.x = (unsigned)bx[0] | ((unsigned)bx[1] << 16);
    w0.y = (unsigned)bx[2] | ((unsigned)bx[3] << 16);
    w0.z = (unsigned)bx[4] | ((unsigned)bx[5] << 16);
    w0.w = (unsigned)bx[6] | ((unsigned)bx[7] << 16);
    w1.x = (unsigned)bx[8] | ((unsigned)bx[9] << 16);
    w1.y = (unsigned)bx[10] | ((unsigned)bx[11] << 16);
    w1.z = (unsigned)bx[12] | ((unsigned)bx[13] << 16);
    w1.w = (unsigned)bx[14] | ((unsigned)bx[15] << 16);
    *(uint4*)(Ab + (b0 ^ sw)) = w0;
    *(uint4*)(Ab + ((b0 + 16) ^ sw)) = w1;
  }
  __syncthreads();

  const int wv = t >> 6, l = t & 63, fr = l & 15;
  { // Phase B+C: z = AX@We^T + be, logits = AX@Wa^T + ba (MFMA), store to LDS
    v4f zac[2][2], lac[2][2];
    #pragma unroll
    for (int a = 0; a < 2; ++a)
      #pragma unroll
      for (int b = 0; b < 2; ++b) {
        zac[a][b] = (v4f){0.f, 0.f, 0.f, 0.f};
        lac[a][b] = (v4f){0.f, 0.f, 0.f, 0.f};
      }
    const int kk = (l >> 4) * 8;
    #pragma unroll
    for (int ks = 0; ks < 4; ++ks) {
      const int k = ks * 32 + kk;
      #pragma unroll
      for (int nj = 0; nj < 2; ++nj) {
        const int col = nj * 64 + wv * 16 + fr;
        v8s bfe = pack8(*(const float4*)(We + col * 128 + k),
                        *(const float4*)(We + col * 128 + k + 4));
        v8s bfa = pack8(*(const float4*)(Wa + col * 128 + k),
                        *(const float4*)(Wa + col * 128 + k + 4));
        #pragma unroll
        for (int mt = 0; mt < 2; ++mt) {
          const int arow = mt * 16 + fr;
          v8s af = *(const v8s*)((char*)axs + (((arow << 8) + k * 2) ^ ((fr & 7) << 4)));
          zac[mt][nj] = __builtin_amdgcn_mfma_f32_16x16x32_bf16(af, bfe, zac[mt][nj], 0, 0, 0);
          lac[mt][nj] = __builtin_amdgcn_mfma_f32_16x16x32_bf16(af, bfa, lac[mt][nj], 0, 0, 0);
        }
      }
    }
    #pragma unroll
    for (int mt = 0; mt < 2; ++mt)
      #pragma unroll
      for (int nj = 0; nj < 2; ++nj)
        #pragma unroll
        for (int r4 = 0; r4 < 4; ++r4) {
          const int row = mt * 16 + (l >> 4) * 4 + r4;
          const int col = nj * 64 + wv * 16 + fr;
          lg[row * 128 + col] = lac[mt][nj][r4] + ba[col];
          zbf[row * 130 + col] = f2bu(zac[mt][nj][r4] + be[col]);
        }
  }
  __syncthreads();

  { // Phase D: softmax, 8 threads per row
    const int r = t >> 3, g = t & 7;
    const float* lp = lg + r * 128 + g * 16;
    float x[16];
    #pragma unroll
    for (int q = 0; q < 4; ++q) {
      float4 v = *(const float4*)(lp + q * 4);
      x[q * 4 + 0] = v.x; x[q * 4 + 1] = v.y; x[q * 4 + 2] = v.z; x[q * 4 + 3] = v.w;
    }
    float mx = x[0];
    #pragma unroll
    for (int j = 1; j < 16; ++j) mx = fmaxf(mx, x[j]);
    #pragma unroll
    for (int d = 1; d < 8; d <<= 1) mx = fmaxf(mx, __shfl_xor(mx, d));
    float sum = 0.f;
    #pragma unroll
    for (int j = 0; j < 16; ++j) { x[j] = __expf(x[j] - mx); sum += x[j]; }
    #pragma unroll
    for (int d = 1; d < 8; d <<= 1) sum += __shfl_xor(sum, d);
    const float inv = 1.0f / sum;
    float* op = sl_out + (size_t)(i0 + r) * 128 + g * 16;
    #pragma unroll
    for (int q = 0; q < 4; ++q) {
      float4 o;
      o.x = x[q * 4 + 0] * inv; o.y = x[q * 4 + 1] * inv;
      o.z = x[q * 4 + 2] * inv; o.w = x[q * 4 + 3] * inv;
      *(float4*)(op + q * 4) = o;
    }
    #pragma unroll
    for (int j = 0; j < 16; ++j) sbf[r * 130 + g * 16 + j] = f2bu(x[j] * inv);
  }
  __syncthreads();

  { // Phase E: transposed bf16 writes (t<128: s_l -> slt; t>=128: z_l -> zlt)
    const int c = t & 127;
    const unsigned short* src = (t < 128) ? sbf : zbf;
    unsigned short* dst = (t < 128) ? slt : zlt;
    unsigned short* o = dst + (size_t)c * 8192 + i0;
    #pragma unroll
    for (int q = 0; q < 4; ++q) {
      uint4 w;
      w.x = (unsigned)src[(q * 8 + 0) * 130 + c] | ((unsigned)src[(q * 8 + 1) * 130 + c] << 16);
      w.y = (unsigned)src[(q * 8 + 2) * 130 + c] | ((unsigned)src[(q * 8 + 3) * 130 + c] << 16);
      w.z = (unsigned)src[(q * 8 + 4) * 130 + c] | ((unsigned)src[(q * 8 + 5) * 130 + c] << 16);
      w.w = (unsigned)src[(q * 8 + 6) * 130 + c] | ((unsigned)src[(q * 8 + 7) * 130 + c] << 16);
      *(uint4*)(o + q * 8) = w;
    }
  }
}

// -------- K6: reduce GEMM2 partials -> bf16 transposed ast [128][8192] --------
__global__ __launch_bounds__(256)
void k_post2(const float* __restrict__ parts, int nsplit, unsigned short* __restrict__ ast) {
  __shared__ unsigned short sb[32 * 130];
  const int t = threadIdx.x;
  const int i0 = blockIdx.x * 32;
  {
    const int r = t >> 3, cg = t & 7;
    const size_t base = (size_t)(i0 + r) * 128 + cg * 16;
    float acc[16];
    #pragma unroll
    for (int q = 0; q < 4; ++q) {
      float4 v = *(const float4*)(parts + base + q * 4);
      acc[q * 4 + 0] = v.x; acc[q * 4 + 1] = v.y;
      acc[q * 4 + 2] = v.z; acc[q * 4 + 3] = v.w;
    }
    for (int s = 1; s < nsplit; ++s) {
      #pragma unroll
      for (int q = 0; q < 4; ++q) {
        float4 v = *(const float4*)(parts + (size_t)s * 1048576 + base + q * 4);
        acc[q * 4 + 0] += v.x; acc[q * 4 + 1] += v.y;
        acc[q * 4 + 2] += v.z; acc[q * 4 + 3] += v.w;
      }
    }
    #pragma unroll
    for (int j = 0; j < 16; ++j) sb[r * 130 + cg * 16 + j] = f2bu(acc[j]);
  }
  __syncthreads();
  if (t < 128) {
    unsigned short* o = ast + (size_t)t * 8192 + i0;
    #pragma unroll
    for (int q = 0; q < 4; ++q) {
      uint4 w;
      w.x = (unsigned)sb[(q * 8 + 0) * 130 + t] | ((unsigned)sb[(q * 8 + 1) * 130 + t] << 16);
      w.y = (unsigned)sb[(q * 8 + 2) * 130 + t] | ((unsigned)sb[(q * 8 + 3) * 130 + t] << 16);
      w.z = (unsigned)sb[(q * 8 + 4) * 130 + t] | ((unsigned)sb[(q * 8 + 5) * 130 + t] << 16);
      w.w = (unsigned)sb[(q * 8 + 6) * 130 + t] | ((unsigned)sb[(q * 8 + 7) * 130 + t] << 16);
      *(uint4*)(o + q * 8) = w;
    }
  }
}

// -------- K7: split-K outer products: X_next = s^T z, A_next = s^T (A s) --------
__global__ __launch_bounds__(256)
void k_outer(const unsigned short* __restrict__ slt, const unsigned short* __restrict__ zlt,
             const unsigned short* __restrict__ ast, float* __restrict__ parts) {
  const int t = threadIdx.x, wv = t >> 6, ln = t & 63;
  const int k0 = blockIdx.x * 128;
  const int lm = ln & 15, lk = (ln >> 4) << 3;
  v4f c1[2][8];
  v4f c2[2][8];
  #pragma unroll
  for (int mt = 0; mt < 2; ++mt)
    #pragma unroll
    for (int nt = 0; nt < 8; ++nt) { c1[mt][nt] = (v4f){0.f,0.f,0.f,0.f}; c2[mt][nt] = (v4f){0.f,0.f,0.f,0.f}; }
  #pragma unroll
  for (int ks = 0; ks < 4; ++ks) {
    int k = k0 + ks * 32 + lk;
    v8s a0 = *(const v8s*)(slt + (size_t)(wv * 32 + lm) * 8192 + k);
    v8s a1 = *(const v8s*)(slt + (size_t)(wv * 32 + 16 + lm) * 8192 + k);
    #pragma unroll
    for (int nt = 0; nt < 8; ++nt) {
      v8s bz = *(const v8s*)(zlt + (size_t)(nt * 16 + lm) * 8192 + k);
      v8s bs = *(const v8s*)(ast + (size_t)(nt * 16 + lm) * 8192 + k);
      c1[0][nt] = __builtin_amdgcn_mfma_f32_16x16x32_bf16(a0, bz, c1[0][nt], 0, 0, 0);
      c1[1][nt] = __builtin_amdgcn_mfma_f32_16x16x32_bf16(a1, bz, c1[1][nt], 0, 0, 0);
      c2[0][nt] = __builtin_amdgcn_mfma_f32_16x16x32_bf16(a0, bs, c2[0][nt], 0, 0, 0);
      c2[1][nt] = __builtin_amdgcn_mfma_f32_16x16x32_bf16(a1, bs, c2[1][nt], 0, 0, 0);
    }
  }
  float* p = parts + (size_t)blockIdx.x * 32768;
  #pragma unroll
  for (int mt = 0; mt < 2; ++mt)
    #pragma unroll
    for (int nt = 0; nt < 8; ++nt)
      #pragma unroll
      for (int r = 0; r < 4; ++r) {
        int m = wv * 32 + mt * 16 + ((ln >> 4) << 2) + r;
        int n = nt * 16 + lm;
        p[m * 128 + n] = c1[mt][nt][r];
        p[16384 + m * 128 + n] = c2[mt][nt][r];
      }
}

// -------- K8: reduce outer partials -> X_next, A_next --------
__global__ __launch_bounds__(256)
void k_reduce(const float* __restrict__ parts, float* __restrict__ out) {
  const int o = blockIdx.x * 256 + threadIdx.x;   // < 32768
  float s = 0.f;
  for (int b = 0; b < 64; ++b) s += parts[(size_t)b * 32768 + o];
  out[o] = s;
}

extern "C" void kernel_launch(void* const* d_in, const int* in_sizes, int n_in,
                              void* d_out, int out_size, void* d_ws, size_t ws_size,
                              hipStream_t stream) {
  (void)in_sizes; (void)n_in; (void)out_size;
  const float* X  = (const float*)d_in[0];
  const float* A  = (const float*)d_in[1];
  const float* We = (const float*)d_in[2];
  const float* be = (const float*)d_in[3];
  const float* Wa = (const float*)d_in[4];
  const float* ba = (const float*)d_in[5];
  float* out = (float*)d_out;
  float* sl = out + 32768;            // s_l region of d_out

  char* ws = (char*)d_ws;
  constexpr size_t OFF_XPT  = 32768;
  constexpr size_t OFF_SLT  = OFF_XPT + 2097152;
  constexpr size_t OFF_ZLT  = OFF_SLT + 2097152;
  constexpr size_t OFF_AST  = OFF_ZLT + 2097152;
  constexpr size_t OFF_PART = OFF_AST + 2097152;     // 64 MB partials region
  constexpr size_t OFF_ABF  = OFF_PART + 67108864;
  constexpr size_t NEED_ABF = OFF_ABF + 134217728ull;

  float*          dinv = (float*)(ws + 0);
  unsigned short* xpt  = (unsigned short*)(ws + OFF_XPT);
  unsigned short* slt  = (unsigned short*)(ws + OFF_SLT);
  unsigned short* zlt  = (unsigned short*)(ws + OFF_ZLT);
  unsigned short* ast  = (unsigned short*)(ws + OFF_AST);
  float*          part = (float*)(ws + OFF_PART);
  unsigned short* abfp = (unsigned short*)(ws + OFF_ABF);

  const bool abf = ws_size >= NEED_ABF;
  const int  sk  = abf ? 8 : 4;

  if (abf) k_degcvt<true><<<8192, 256, 0, stream>>>(A, dinv, abfp);
  else     k_degcvt<false><<<8192, 256, 0, stream>>>(A, dinv, abfp);

  k_transpose<true><<<256, 256, 0, stream>>>(X, xpt, dinv);

  if (abf) k_gemm_lds<<<dim3(64, 8), 512, 0, stream>>>(abfp, xpt, part);
  else     k_gemm_f32<<<dim3(64, 4), 512, 0, stream>>>(A, xpt, part);

  k_post1<<<256, 256, 0, stream>>>(part, sk, dinv, X, We, be, Wa, ba, sl, slt, zlt);

  if (abf) k_gemm_lds<<<dim3(64, 8), 512, 0, stream>>>(abfp, slt, part);
  else     k_gemm_f32<<<dim3(64, 4), 512, 0, stream>>>(A, slt, part);

  k_post2<<<256, 256, 0, stream>>>(part, sk, ast);
  k_outer<<<64, 256, 0, stream>>>(slt, zlt, ast, part);
  k_reduce<<<128, 256, 0, stream>>>(part, out);
}